// Round 2
// baseline (5699.444 us; speedup 1.0000x reference)
//
#include <hip/hip_runtime.h>
#include <cstddef>

#define L 2048
#define B 2
#define C 1024
#define H 16
#define HD 64
#define BH (B * H)
#define C3 (3 * C)
#define M (L * B)  // 4096 rows of the (L*B, C) activation matrix

// ---------------------------------------------------------------------------
// Tiled fp32 GEMM: 64x64 tile, BK=16, 256 threads, 4x4 register tile/thread.
// ---------------------------------------------------------------------------

__global__ __launch_bounds__(256) void qkv_gemm(
    const float* __restrict__ A,      // x, (M, C) row-major
    const float* __restrict__ W,      // Wqkv, (C, 3C) row-major
    const float* __restrict__ bias,   // bqkv (3C)
    float* __restrict__ qs,           // (BH, L, HD)  scaled
    float* __restrict__ kt,           // (BH, HD, L)  transposed
    float* __restrict__ v)            // (BH, L, HD)
{
    __shared__ float As[16][65];
    __shared__ float Bs[16][64];
    const int tid = threadIdx.x;
    const int tx = tid & 15, ty = tid >> 4;
    const int bm = blockIdx.y * 64;
    const int bn = blockIdx.x * 64;

    const int a_r = tid >> 2;          // 0..63
    const int a_c0 = (tid & 3) * 4;    // 0,4,8,12
    const int b_c = tid & 63;
    const int b_r0 = tid >> 6;         // 0..3

    float acc[4][4] = {};

    for (int k0 = 0; k0 < C; k0 += 16) {
        float4 a4 = *(const float4*)(A + (size_t)(bm + a_r) * C + k0 + a_c0);
        As[a_c0 + 0][a_r] = a4.x;
        As[a_c0 + 1][a_r] = a4.y;
        As[a_c0 + 2][a_r] = a4.z;
        As[a_c0 + 3][a_r] = a4.w;
#pragma unroll
        for (int rr = 0; rr < 4; ++rr) {
            int b_r = b_r0 + rr * 4;
            Bs[b_r][b_c] = W[(size_t)(k0 + b_r) * C3 + bn + b_c];
        }
        __syncthreads();
#pragma unroll
        for (int kk = 0; kk < 16; ++kk) {
            float a[4], b[4];
#pragma unroll
            for (int i = 0; i < 4; ++i) a[i] = As[kk][ty * 4 + i];
#pragma unroll
            for (int j = 0; j < 4; ++j) b[j] = Bs[kk][tx * 4 + j];
#pragma unroll
            for (int i = 0; i < 4; ++i)
#pragma unroll
                for (int j = 0; j < 4; ++j) acc[i][j] += a[i] * b[j];
        }
        __syncthreads();
    }

    const int part = bn >> 10;          // 0=q 1=k 2=v (BN=64 never straddles)
    const int h = (bn & 1023) >> 6;
#pragma unroll
    for (int i = 0; i < 4; ++i) {
        int row = bm + ty * 4 + i;
        int l = row >> 1, bb = row & 1;
        int bh = bb * H + h;
#pragma unroll
        for (int j = 0; j < 4; ++j) {
            int d = tx * 4 + j;
            float val = acc[i][j] + bias[bn + d];
            if (part == 0)
                qs[((size_t)bh * L + l) * HD + d] = val * 0.125f;  // HD^-0.5
            else if (part == 1)
                kt[((size_t)bh * HD + d) * L + l] = val;
            else
                v[((size_t)bh * L + l) * HD + d] = val;
        }
    }
}

__global__ __launch_bounds__(256) void out_gemm(
    const float* __restrict__ A,      // o, (M, C)
    const float* __restrict__ W,      // Wout (C, C)
    const float* __restrict__ bias,   // bout
    float* __restrict__ out)          // (M, C) -> (L,B,C) flat
{
    __shared__ float As[16][65];
    __shared__ float Bs[16][64];
    const int tid = threadIdx.x;
    const int tx = tid & 15, ty = tid >> 4;
    const int bm = blockIdx.y * 64;
    const int bn = blockIdx.x * 64;

    const int a_r = tid >> 2;
    const int a_c0 = (tid & 3) * 4;
    const int b_c = tid & 63;
    const int b_r0 = tid >> 6;

    float acc[4][4] = {};

    for (int k0 = 0; k0 < C; k0 += 16) {
        float4 a4 = *(const float4*)(A + (size_t)(bm + a_r) * C + k0 + a_c0);
        As[a_c0 + 0][a_r] = a4.x;
        As[a_c0 + 1][a_r] = a4.y;
        As[a_c0 + 2][a_r] = a4.z;
        As[a_c0 + 3][a_r] = a4.w;
#pragma unroll
        for (int rr = 0; rr < 4; ++rr) {
            int b_r = b_r0 + rr * 4;
            Bs[b_r][b_c] = W[(size_t)(k0 + b_r) * C + bn + b_c];
        }
        __syncthreads();
#pragma unroll
        for (int kk = 0; kk < 16; ++kk) {
            float a[4], b[4];
#pragma unroll
            for (int i = 0; i < 4; ++i) a[i] = As[kk][ty * 4 + i];
#pragma unroll
            for (int j = 0; j < 4; ++j) b[j] = Bs[kk][tx * 4 + j];
#pragma unroll
            for (int i = 0; i < 4; ++i)
#pragma unroll
                for (int j = 0; j < 4; ++j) acc[i][j] += a[i] * b[j];
        }
        __syncthreads();
    }

#pragma unroll
    for (int i = 0; i < 4; ++i) {
        int row = bm + ty * 4 + i;
#pragma unroll
        for (int j = 0; j < 4; ++j) {
            int col = bn + tx * 4 + j;
            out[(size_t)row * C + col] = acc[i][j] + bias[col];
        }
    }
}

// ---------------------------------------------------------------------------
// Pass 1: per (bh, q) online softmax stats (m, l) over masked scores.
// Masks arrive as int32 (bool uploaded as int).
// ---------------------------------------------------------------------------
__global__ __launch_bounds__(256) void attn_pass1(
    const float* __restrict__ qs, const float* __restrict__ kt,
    const int* __restrict__ amask,
    const int* __restrict__ kpm,
    float* __restrict__ ml)
{
    const int q = blockIdx.x;
    const int bh = blockIdx.y;
    const int b = bh >> 4;
    const int t = threadIdx.x;

    __shared__ float qv[HD];
    __shared__ float sm[256], sl[256];
    if (t < HD) qv[t] = qs[((size_t)bh * L + q) * HD + t];
    __syncthreads();

    const float* ktb = kt + (size_t)bh * HD * L;
    const int* am = amask + (size_t)q * L;
    const int* kp = kpm + (size_t)b * L;

    float m = -3.0e38f, lsum = 0.f;
    for (int key = t; key < L; key += 256) {
        if (am[key] | kp[key]) continue;
        float s = 0.f;
#pragma unroll 8
        for (int d = 0; d < HD; ++d) s += qv[d] * ktb[(size_t)d * L + key];
        float nm = fmaxf(m, s);
        lsum = lsum * __expf(m - nm) + __expf(s - nm);
        m = nm;
    }
    sm[t] = m;
    sl[t] = lsum;
    __syncthreads();
    for (int off = 128; off > 0; off >>= 1) {
        if (t < off) {
            float m1 = sm[t], m2 = sm[t + off];
            float nm = fmaxf(m1, m2);
            sl[t] = sl[t] * __expf(m1 - nm) + sl[t + off] * __expf(m2 - nm);
            sm[t] = nm;
        }
        __syncthreads();
    }
    if (t == 0) {
        ml[((size_t)bh * L + q) * 2] = sm[0];
        ml[((size_t)bh * L + q) * 2 + 1] = sl[0];
    }
}

// ---------------------------------------------------------------------------
// Pass 2: per (b, q), all heads — P chunks in LDS, attn_avg direct write,
// O accumulation in registers.
// ---------------------------------------------------------------------------
__global__ __launch_bounds__(256) void attn_pass2(
    const float* __restrict__ qs, const float* __restrict__ kt,
    const float* __restrict__ v, const float* __restrict__ ml,
    const int* __restrict__ amask,
    const int* __restrict__ kpm,
    float* __restrict__ o, float* __restrict__ attn_avg)
{
    const int q = blockIdx.x;
    const int b = blockIdx.y;
    const int t = threadIdx.x;

    __shared__ float qv[H * HD];     // [h][d]
    __shared__ float mh[H], lh[H];
    __shared__ float pch[H][256];

    for (int e = t; e < H * HD; e += 256) {
        int h = e >> 6, d = e & 63;
        qv[e] = qs[(((size_t)(b * H + h) * L + q) * HD) + d];
    }
    if (t < H) {
        mh[t] = ml[((size_t)(b * H + t) * L + q) * 2];
        lh[t] = ml[((size_t)(b * H + t) * L + q) * 2 + 1];
    }
    __syncthreads();

    const int* am = amask + (size_t)q * L;
    const int* kp = kpm + (size_t)b * L;

    float oacc[4] = {0.f, 0.f, 0.f, 0.f};

    for (int c0 = 0; c0 < L; c0 += 256) {
        const int key = c0 + t;
        const bool masked = (am[key] | kp[key]) != 0;
        // scores -> probabilities for all heads at this key
        for (int h = 0; h < H; ++h) {
            float p = 0.f;
            if (!masked) {
                const float* ktb = kt + (size_t)(b * H + h) * HD * L;
                float s = 0.f;
#pragma unroll 8
                for (int d = 0; d < HD; ++d)
                    s += qv[h * HD + d] * ktb[(size_t)d * L + key];
                p = __expf(s - mh[h]) / lh[h];
            }
            pch[h][t] = p;
        }
        __syncthreads();

        // attn_avg — every element written (d_out is poisoned)
        float av = 0.f;
#pragma unroll
        for (int h = 0; h < H; ++h) av += pch[h][t];
        attn_avg[((size_t)b * L + q) * L + key] = av * (1.f / H);

        // O accumulation: thread owns 4 (h,d) slots
#pragma unroll
        for (int r = 0; r < 4; ++r) {
            int e = t + 256 * r;
            int h = e >> 6, d = e & 63;
            const float* vb = v + ((size_t)(b * H + h) * L + c0) * HD;
            float acc = oacc[r];
            for (int kk = 0; kk < 256; ++kk) {
                float p = pch[h][kk];          // wave-uniform (64 lanes = 1 h)
                if (p != 0.f) acc += p * vb[(size_t)kk * HD + d];
            }
            oacc[r] = acc;
        }
        __syncthreads();
    }

#pragma unroll
    for (int r = 0; r < 4; ++r) {
        int e = t + 256 * r;
        o[((size_t)q * B + b) * C + e] = oacc[r];
    }
}

// ---------------------------------------------------------------------------

extern "C" void kernel_launch(void* const* d_in, const int* in_sizes, int n_in,
                              void* d_out, int out_size, void* d_ws, size_t ws_size,
                              hipStream_t stream) {
    const float* x     = (const float*)d_in[0];
    const float* Wqkv  = (const float*)d_in[1];
    const float* bqkv  = (const float*)d_in[2];
    const float* Wout  = (const float*)d_in[3];
    const float* bout  = (const float*)d_in[4];
    const int* amask   = (const int*)d_in[5];
    const int* kpm     = (const int*)d_in[6];

    float* out      = (float*)d_out;                       // (L,B,C)
    float* attn_avg = out + (size_t)L * B * C;             // (B,L,L)

    float* ws = (float*)d_ws;
    const size_t SEG = (size_t)BH * L * HD;                // 4,194,304
    float* qs = ws;
    float* kt = qs + SEG;
    float* vv = kt + SEG;
    float* o  = vv + SEG;
    float* ml = o + SEG;

    qkv_gemm<<<dim3(C3 / 64, M / 64), 256, 0, stream>>>(x, Wqkv, bqkv, qs, kt, vv);
    attn_pass1<<<dim3(L, BH), 256, 0, stream>>>(qs, kt, amask, kpm, ml);
    attn_pass2<<<dim3(L, B), 256, 0, stream>>>(qs, kt, vv, ml, amask, kpm, o, attn_avg);
    out_gemm<<<dim3(C / 64, M / 64), 256, 0, stream>>>(o, Wout, bout, out);
}

// Round 3
// 934.022 us; speedup vs baseline: 6.1020x; 6.1020x over previous
//
#include <hip/hip_runtime.h>
#include <cstddef>

#define L 2048
#define B 2
#define C 1024
#define H 16
#define HD 64
#define BH (B * H)
#define C3 (3 * C)
#define M (L * B)

typedef __attribute__((ext_vector_type(8))) short bf16x8;
typedef __attribute__((ext_vector_type(4))) float f32x4;

__device__ __forceinline__ short f2bf(float f) {
    unsigned u = __builtin_bit_cast(unsigned, f);
    unsigned r = (u + 0x7FFFu + ((u >> 16) & 1u)) >> 16;
    return (short)r;
}

// ---------------------------------------------------------------------------
// QKV GEMM (fp32 compute), epilogue writes bf16 q/k/v in MFMA-friendly layouts
//   qs (bh, L, HD) bf16, scaled by HD^-0.5
//   ks (bh, L, HD) bf16
//   vt (bh, HD, L) bf16   (transposed so PV B-fragments are contiguous)
// ---------------------------------------------------------------------------
__global__ __launch_bounds__(256) void qkv_gemm(
    const float* __restrict__ A, const float* __restrict__ W,
    const float* __restrict__ bias,
    short* __restrict__ qs, short* __restrict__ ks, short* __restrict__ vt)
{
    __shared__ float As[16][65];
    __shared__ float Bs[16][64];
    const int tid = threadIdx.x;
    const int tx = tid & 15, ty = tid >> 4;
    const int bm = blockIdx.y * 64;
    const int bn = blockIdx.x * 64;

    const int a_r = tid >> 2;
    const int a_c0 = (tid & 3) * 4;
    const int b_c = tid & 63;
    const int b_r0 = tid >> 6;

    float acc[4][4] = {};

    for (int k0 = 0; k0 < C; k0 += 16) {
        float4 a4 = *(const float4*)(A + (size_t)(bm + a_r) * C + k0 + a_c0);
        As[a_c0 + 0][a_r] = a4.x;
        As[a_c0 + 1][a_r] = a4.y;
        As[a_c0 + 2][a_r] = a4.z;
        As[a_c0 + 3][a_r] = a4.w;
#pragma unroll
        for (int rr = 0; rr < 4; ++rr) {
            int b_r = b_r0 + rr * 4;
            Bs[b_r][b_c] = W[(size_t)(k0 + b_r) * C3 + bn + b_c];
        }
        __syncthreads();
#pragma unroll
        for (int kk = 0; kk < 16; ++kk) {
            float a[4], b[4];
#pragma unroll
            for (int i = 0; i < 4; ++i) a[i] = As[kk][ty * 4 + i];
#pragma unroll
            for (int j = 0; j < 4; ++j) b[j] = Bs[kk][tx * 4 + j];
#pragma unroll
            for (int i = 0; i < 4; ++i)
#pragma unroll
                for (int j = 0; j < 4; ++j) acc[i][j] += a[i] * b[j];
        }
        __syncthreads();
    }

    const int part = bn >> 10;
    const int h = (bn & 1023) >> 6;
#pragma unroll
    for (int i = 0; i < 4; ++i) {
        int row = bm + ty * 4 + i;
        int l = row >> 1, bb = row & 1;
        int bh = bb * H + h;
#pragma unroll
        for (int j = 0; j < 4; ++j) {
            int d = tx * 4 + j;
            float val = acc[i][j] + bias[bn + d];
            if (part == 0)
                qs[((size_t)bh * L + l) * HD + d] = f2bf(val * 0.125f);
            else if (part == 1)
                ks[((size_t)bh * L + l) * HD + d] = f2bf(val);
            else
                vt[((size_t)bh * HD + d) * L + l] = f2bf(val);
        }
    }
}

__global__ __launch_bounds__(256) void out_gemm(
    const float* __restrict__ A, const float* __restrict__ W,
    const float* __restrict__ bias, float* __restrict__ out)
{
    __shared__ float As[16][65];
    __shared__ float Bs[16][64];
    const int tid = threadIdx.x;
    const int tx = tid & 15, ty = tid >> 4;
    const int bm = blockIdx.y * 64;
    const int bn = blockIdx.x * 64;

    const int a_r = tid >> 2;
    const int a_c0 = (tid & 3) * 4;
    const int b_c = tid & 63;
    const int b_r0 = tid >> 6;

    float acc[4][4] = {};

    for (int k0 = 0; k0 < C; k0 += 16) {
        float4 a4 = *(const float4*)(A + (size_t)(bm + a_r) * C + k0 + a_c0);
        As[a_c0 + 0][a_r] = a4.x;
        As[a_c0 + 1][a_r] = a4.y;
        As[a_c0 + 2][a_r] = a4.z;
        As[a_c0 + 3][a_r] = a4.w;
#pragma unroll
        for (int rr = 0; rr < 4; ++rr) {
            int b_r = b_r0 + rr * 4;
            Bs[b_r][b_c] = W[(size_t)(k0 + b_r) * C + bn + b_c];
        }
        __syncthreads();
#pragma unroll
        for (int kk = 0; kk < 16; ++kk) {
            float a[4], b[4];
#pragma unroll
            for (int i = 0; i < 4; ++i) a[i] = As[kk][ty * 4 + i];
#pragma unroll
            for (int j = 0; j < 4; ++j) b[j] = Bs[kk][tx * 4 + j];
#pragma unroll
            for (int i = 0; i < 4; ++i)
#pragma unroll
                for (int j = 0; j < 4; ++j) acc[i][j] += a[i] * b[j];
        }
        __syncthreads();
    }

#pragma unroll
    for (int i = 0; i < 4; ++i) {
        int row = bm + ty * 4 + i;
#pragma unroll
        for (int j = 0; j < 4; ++j) {
            int col = bn + tx * 4 + j;
            out[(size_t)row * C + col] = acc[i][j] + bias[col];
        }
    }
}

// ---------------------------------------------------------------------------
// attn_stats: per (q-tile 64, bh). MFMA QK^T, online (m,l) per row.
// Causal mask computed analytically (attn_mask is triu(k=1)); kpm from input.
// ---------------------------------------------------------------------------
__global__ __launch_bounds__(256) void attn_stats(
    const short* __restrict__ qs, const short* __restrict__ ks,
    const int* __restrict__ kpm, float* __restrict__ ml)
{
    const int qt = blockIdx.x, bh = blockIdx.y, b = bh >> 4;
    const int q0 = qt * 64;
    const int t = threadIdx.x;
    const int w = t >> 6, lane = t & 63;
    const int l15 = lane & 15, quad = lane >> 4;
    const int qbase = q0 + w * 16;

    const short* qrow = qs + ((size_t)bh * L + qbase + l15) * HD + quad * 8;
    bf16x8 a0 = *(const bf16x8*)(qrow);
    bf16x8 a1 = *(const bf16x8*)(qrow + 32);

    float m[4], lsum[4];
#pragma unroll
    for (int r = 0; r < 4; ++r) { m[r] = -3.0e38f; lsum[r] = 0.f; }

    const int ktiles = qt + 1;   // causal: keys <= q0+63
    for (int kt = 0; kt < ktiles; ++kt) {
        const int k0 = kt * 64;
        f32x4 sc[4];
        int kp[4];
#pragma unroll
        for (int nt = 0; nt < 4; ++nt) {
            const short* kr = ks + ((size_t)bh * L + k0 + nt * 16 + l15) * HD + quad * 8;
            bf16x8 b0 = *(const bf16x8*)(kr);
            bf16x8 b1 = *(const bf16x8*)(kr + 32);
            f32x4 c = {0.f, 0.f, 0.f, 0.f};
            c = __builtin_amdgcn_mfma_f32_16x16x32_bf16(a0, b0, c, 0, 0, 0);
            c = __builtin_amdgcn_mfma_f32_16x16x32_bf16(a1, b1, c, 0, 0, 0);
            sc[nt] = c;
            kp[nt] = kpm[(size_t)b * L + k0 + nt * 16 + l15];
        }
#pragma unroll
        for (int r = 0; r < 4; ++r) {
            const int q = qbase + quad * 4 + r;
            float sv[4];
            float tm = -3.0e38f;
#pragma unroll
            for (int nt = 0; nt < 4; ++nt) {
                int k = k0 + nt * 16 + l15;
                bool mk = (k > q) || (kp[nt] != 0);
                float s = mk ? -3.0e38f : sc[nt][r];
                sv[nt] = s;
                tm = fmaxf(tm, s);
            }
            tm = fmaxf(tm, __shfl_xor(tm, 1, 16));
            tm = fmaxf(tm, __shfl_xor(tm, 2, 16));
            tm = fmaxf(tm, __shfl_xor(tm, 4, 16));
            tm = fmaxf(tm, __shfl_xor(tm, 8, 16));
            float nm = fmaxf(m[r], tm);
            float se = 0.f;
#pragma unroll
            for (int nt = 0; nt < 4; ++nt)
                se += (sv[nt] > -1.0e37f) ? __expf(sv[nt] - nm) : 0.f;
            se += __shfl_xor(se, 1, 16);
            se += __shfl_xor(se, 2, 16);
            se += __shfl_xor(se, 4, 16);
            se += __shfl_xor(se, 8, 16);
            lsum[r] = lsum[r] * __expf(m[r] - nm) + se;
            m[r] = nm;
        }
    }

    if (l15 == 0) {
#pragma unroll
        for (int r = 0; r < 4; ++r) {
            int q = qbase + quad * 4 + r;
            ml[((size_t)bh * L + q) * 2] = m[r];
            ml[((size_t)bh * L + q) * 2 + 1] = lsum[r];
        }
    }
}

// ---------------------------------------------------------------------------
// attn_pv: per (q-tile 16, b). 512 thr = 8 waves x 2 heads. MFMA scores ->
// P -> LDS (C->A layout) -> MFMA PV. attn_avg reduced across waves in LDS.
// ---------------------------------------------------------------------------
#define PS 72   // Plds row stride (shorts): 144B = 16B-multiple, conflict-safe
__global__ __launch_bounds__(512) void attn_pv(
    const short* __restrict__ qs, const short* __restrict__ ks,
    const short* __restrict__ vt, const float* __restrict__ ml,
    const int* __restrict__ kpm,
    float* __restrict__ o, float* __restrict__ attn_avg)
{
    const int qt = blockIdx.x, b = blockIdx.y;
    const int q0 = qt * 16;
    const int t = threadIdx.x;
    const int w = t >> 6, lane = t & 63;
    const int l15 = lane & 15, quad = lane >> 4;

    __shared__ short Plds[8][16 * PS];
    __shared__ float avg[8][16][66];
    __shared__ float mls[H][16][2];

    if (t < 256) {
        int h = t >> 4, qq = t & 15;
        mls[h][qq][0] = ml[((size_t)(b * H + h) * L + q0 + qq) * 2];
        mls[h][qq][1] = ml[((size_t)(b * H + h) * L + q0 + qq) * 2 + 1];
    }
    __syncthreads();

    const int h0 = w * 2;
    bf16x8 aq[2][2];
#pragma unroll
    for (int hh = 0; hh < 2; ++hh) {
        const short* qr = qs + ((size_t)(b * H + h0 + hh) * L + q0 + l15) * HD + quad * 8;
        aq[hh][0] = *(const bf16x8*)(qr);
        aq[hh][1] = *(const bf16x8*)(qr + 32);
    }
    float mreg[2][4], il[2][4];
#pragma unroll
    for (int hh = 0; hh < 2; ++hh)
#pragma unroll
        for (int r = 0; r < 4; ++r) {
            mreg[hh][r] = mls[h0 + hh][quad * 4 + r][0];
            float lv = mls[h0 + hh][quad * 4 + r][1];
            il[hh][r] = (lv > 0.f) ? (1.f / lv) : 0.f;
        }

    f32x4 oacc[2][4];
#pragma unroll
    for (int hh = 0; hh < 2; ++hh)
#pragma unroll
        for (int nt = 0; nt < 4; ++nt) oacc[hh][nt] = (f32x4){0.f, 0.f, 0.f, 0.f};

    const int ktiles = (q0 >> 6) + 1;
    for (int kt = 0; kt < ktiles; ++kt) {
        const int k0 = kt * 64;
        int kp[4];
#pragma unroll
        for (int nt = 0; nt < 4; ++nt)
            kp[nt] = kpm[(size_t)b * L + k0 + nt * 16 + l15];

        f32x4 psum[4];
#pragma unroll
        for (int nt = 0; nt < 4; ++nt) psum[nt] = (f32x4){0.f, 0.f, 0.f, 0.f};

#pragma unroll
        for (int hh = 0; hh < 2; ++hh) {
            const int head = h0 + hh;
            const size_t kbase = (size_t)(b * H + head) * L * HD;
            f32x4 sc[4];
#pragma unroll
            for (int nt = 0; nt < 4; ++nt) {
                const short* kr = ks + kbase + (size_t)(k0 + nt * 16 + l15) * HD + quad * 8;
                f32x4 c = {0.f, 0.f, 0.f, 0.f};
                c = __builtin_amdgcn_mfma_f32_16x16x32_bf16(aq[hh][0], *(const bf16x8*)(kr), c, 0, 0, 0);
                c = __builtin_amdgcn_mfma_f32_16x16x32_bf16(aq[hh][1], *(const bf16x8*)(kr + 32), c, 0, 0, 0);
                sc[nt] = c;
            }
            // P + stash to LDS in (q,key) layout
#pragma unroll
            for (int nt = 0; nt < 4; ++nt) {
#pragma unroll
                for (int r = 0; r < 4; ++r) {
                    int k = k0 + nt * 16 + l15;
                    int q = q0 + quad * 4 + r;
                    bool mk = (k > q) || (kp[nt] != 0);
                    float p = mk ? 0.f : __expf(sc[nt][r] - mreg[hh][r]) * il[hh][r];
                    psum[nt][r] += p;
                    Plds[w][(quad * 4 + r) * PS + nt * 16 + l15] = f2bf(p);
                }
            }
            __asm__ volatile("s_waitcnt lgkmcnt(0)" ::: "memory");
            bf16x8 pa0 = *(const bf16x8*)(&Plds[w][l15 * PS + quad * 8]);
            bf16x8 pa1 = *(const bf16x8*)(&Plds[w][l15 * PS + 32 + quad * 8]);
            __asm__ volatile("s_waitcnt lgkmcnt(0)" ::: "memory");
            // PV
            const size_t vbase = (size_t)(b * H + head) * HD * L;
#pragma unroll
            for (int nt = 0; nt < 4; ++nt) {
                const short* vr = vt + vbase + (size_t)(nt * 16 + l15) * L + k0;
                oacc[hh][nt] = __builtin_amdgcn_mfma_f32_16x16x32_bf16(
                    pa0, *(const bf16x8*)(vr + quad * 8), oacc[hh][nt], 0, 0, 0);
                oacc[hh][nt] = __builtin_amdgcn_mfma_f32_16x16x32_bf16(
                    pa1, *(const bf16x8*)(vr + 32 + quad * 8), oacc[hh][nt], 0, 0, 0);
            }
        }

        // cross-wave attn_avg reduction
#pragma unroll
        for (int nt = 0; nt < 4; ++nt)
#pragma unroll
            for (int r = 0; r < 4; ++r)
                avg[w][quad * 4 + r][nt * 16 + l15] = psum[nt][r];
        __syncthreads();
        {
            int q = t >> 5, kk = (t & 31) * 2;
            float s0 = 0.f, s1 = 0.f;
#pragma unroll
            for (int ww = 0; ww < 8; ++ww) {
                s0 += avg[ww][q][kk];
                s1 += avg[ww][q][kk + 1];
            }
            float2* dst = (float2*)(attn_avg + ((size_t)b * L + q0 + q) * L + k0 + kk);
            *dst = make_float2(s0 * (1.f / H), s1 * (1.f / H));
        }
        __syncthreads();
    }

    // zero-fill causal tail of attn_avg (d_out is poisoned; must write zeros)
    const int kfill = ktiles * 64;
    for (int qq = 0; qq < 16; ++qq) {
        for (int c0 = kfill + t * 4; c0 < L; c0 += 2048) {
            float4* dst = (float4*)(attn_avg + ((size_t)b * L + q0 + qq) * L + c0);
            *dst = make_float4(0.f, 0.f, 0.f, 0.f);
        }
    }

    // write O (fp32) as rows (l*B+b, C)
#pragma unroll
    for (int hh = 0; hh < 2; ++hh)
#pragma unroll
        for (int nt = 0; nt < 4; ++nt)
#pragma unroll
            for (int r = 0; r < 4; ++r) {
                int q = q0 + quad * 4 + r;
                int col = (h0 + hh) * HD + nt * 16 + l15;
                o[((size_t)q * B + b) * C + col] = oacc[hh][nt][r];
            }
}

// ---------------------------------------------------------------------------

extern "C" void kernel_launch(void* const* d_in, const int* in_sizes, int n_in,
                              void* d_out, int out_size, void* d_ws, size_t ws_size,
                              hipStream_t stream) {
    const float* x     = (const float*)d_in[0];
    const float* Wqkv  = (const float*)d_in[1];
    const float* bqkv  = (const float*)d_in[2];
    const float* Wout  = (const float*)d_in[3];
    const float* bout  = (const float*)d_in[4];
    const int* kpm     = (const int*)d_in[6];

    float* out      = (float*)d_out;
    float* attn_avg = out + (size_t)L * B * C;

    const size_t SEG = (size_t)BH * L * HD;      // 4,194,304 elements
    float* o  = (float*)d_ws;                    // fp32 (M, C)
    float* ml = o + SEG;                         // (BH, L, 2) fp32
    short* qs = (short*)(ml + (size_t)BH * L * 2);
    short* ks = qs + SEG;
    short* vt = ks + SEG;

    qkv_gemm<<<dim3(C3 / 64, M / 64), 256, 0, stream>>>(x, Wqkv, bqkv, qs, ks, vt);
    attn_stats<<<dim3(L / 64, BH), 256, 0, stream>>>(qs, ks, kpm, ml);
    attn_pv<<<dim3(L / 16, B), 512, 0, stream>>>(qs, ks, vt, ml, kpm, o, attn_avg);
    out_gemm<<<dim3(C / 64, M / 64), 256, 0, stream>>>(o, Wout, bout, out);
}

// Round 4
// 545.565 us; speedup vs baseline: 10.4469x; 1.7120x over previous
//
#include <hip/hip_runtime.h>
#include <cstddef>

#define L 2048
#define B 2
#define C 1024
#define H 16
#define HD 64
#define BH (B * H)
#define C3 (3 * C)
#define M (L * B)

typedef __attribute__((ext_vector_type(8))) short bf16x8;
typedef __attribute__((ext_vector_type(4))) float f32x4;

__device__ __forceinline__ short f2bf(float f) {
    unsigned u = __builtin_bit_cast(unsigned, f);
    unsigned r = (u + 0x7FFFu + ((u >> 16) & 1u)) >> 16;
    return (short)r;
}

// ---------------------------------------------------------------------------
// Prep: flat fp32 -> bf16 cast (x), and 32x32 transpose-cast for weights.
// ---------------------------------------------------------------------------
__global__ __launch_bounds__(256) void cast_bf16(
    const float* __restrict__ src, short* __restrict__ dst)
{
    const size_t i = ((size_t)blockIdx.x * 256 + threadIdx.x) * 8;
    float4 a = *(const float4*)(src + i);
    float4 b = *(const float4*)(src + i + 4);
    bf16x8 o;
    o[0] = f2bf(a.x); o[1] = f2bf(a.y); o[2] = f2bf(a.z); o[3] = f2bf(a.w);
    o[4] = f2bf(b.x); o[5] = f2bf(b.y); o[6] = f2bf(b.z); o[7] = f2bf(b.w);
    *(bf16x8*)(dst + i) = o;
}

// src (R x Ccols) fp32 row-major  ->  dst (Ccols x R) bf16 row-major
__global__ __launch_bounds__(256) void transpose_cast(
    const float* __restrict__ src, short* __restrict__ dst, int R, int Ccols)
{
    __shared__ float tile[32][33];
    const int bx = blockIdx.x * 32;   // col base in src
    const int by = blockIdx.y * 32;   // row base in src
    const int t = threadIdx.x;
    const int tr = t >> 5, tc = t & 31;
#pragma unroll
    for (int p = 0; p < 4; ++p)
        tile[tr + p * 8][tc] = src[(size_t)(by + tr + p * 8) * Ccols + bx + tc];
    __syncthreads();
#pragma unroll
    for (int p = 0; p < 4; ++p)
        dst[(size_t)(bx + tr + p * 8) * R + by + tc] = f2bf(tile[tc][tr + p * 8]);
}

// ---------------------------------------------------------------------------
// bf16 MFMA GEMM, 128x128 tile, BK=32, 256 thr = 4 waves (2x2 of 64x64).
// A (M,K) bf16 row-major; Bt (N,K) bf16 row-major (i.e., B transposed).
// ---------------------------------------------------------------------------
__global__ __launch_bounds__(256) void qkv_gemm_mfma(
    const short* __restrict__ A, const short* __restrict__ Bt,
    const float* __restrict__ bias,
    short* __restrict__ qs, short* __restrict__ ks, short* __restrict__ vt)
{
    __shared__ short As[128 * 32];
    __shared__ short Bs[128 * 32];
    const int t = threadIdx.x;
    const int w = t >> 6, lane = t & 63;
    const int l15 = lane & 15, quad = lane >> 4;
    const int wr = w >> 1, wc = w & 1;
    const int bm = blockIdx.y * 128, bn = blockIdx.x * 128;
    const int sr = t >> 2, sc = (t & 3) * 8;

    f32x4 acc[4][4];
#pragma unroll
    for (int i = 0; i < 4; ++i)
#pragma unroll
        for (int j = 0; j < 4; ++j) acc[i][j] = (f32x4){0.f, 0.f, 0.f, 0.f};

    for (int k0 = 0; k0 < C; k0 += 32) {
        *(bf16x8*)&As[sr * 32 + sc]        = *(const bf16x8*)&A[(size_t)(bm + sr) * C + k0 + sc];
        *(bf16x8*)&As[(sr + 64) * 32 + sc] = *(const bf16x8*)&A[(size_t)(bm + sr + 64) * C + k0 + sc];
        *(bf16x8*)&Bs[sr * 32 + sc]        = *(const bf16x8*)&Bt[(size_t)(bn + sr) * C + k0 + sc];
        *(bf16x8*)&Bs[(sr + 64) * 32 + sc] = *(const bf16x8*)&Bt[(size_t)(bn + sr + 64) * C + k0 + sc];
        __syncthreads();
        bf16x8 af[4], bfr[4];
#pragma unroll
        for (int i = 0; i < 4; ++i)
            af[i] = *(const bf16x8*)&As[(wr * 64 + i * 16 + l15) * 32 + quad * 8];
#pragma unroll
        for (int j = 0; j < 4; ++j)
            bfr[j] = *(const bf16x8*)&Bs[(wc * 64 + j * 16 + l15) * 32 + quad * 8];
#pragma unroll
        for (int i = 0; i < 4; ++i)
#pragma unroll
            for (int j = 0; j < 4; ++j)
                acc[i][j] = __builtin_amdgcn_mfma_f32_16x16x32_bf16(af[i], bfr[j], acc[i][j], 0, 0, 0);
        __syncthreads();
    }

#pragma unroll
    for (int i = 0; i < 4; ++i) {
#pragma unroll
        for (int j = 0; j < 4; ++j) {
            const int n = bn + wc * 64 + j * 16 + l15;
            const int part = n >> 10, rem = n & 1023;
            const int h = rem >> 6, d = rem & 63;
            const float bv = bias[n];
#pragma unroll
            for (int r = 0; r < 4; ++r) {
                const int m = bm + wr * 64 + i * 16 + quad * 4 + r;
                const int l = m >> 1, bb = m & 1, bh = bb * H + h;
                float val = acc[i][j][r] + bv;
                if (part == 0)
                    qs[((size_t)bh * L + l) * HD + d] = f2bf(val * 0.125f);
                else if (part == 1)
                    ks[((size_t)bh * L + l) * HD + d] = f2bf(val);
                else
                    vt[((size_t)bh * HD + d) * L + l] = f2bf(val);
            }
        }
    }
}

__global__ __launch_bounds__(256) void out_gemm_mfma(
    const short* __restrict__ A, const short* __restrict__ Bt,
    const float* __restrict__ bias, float* __restrict__ out)
{
    __shared__ short As[128 * 32];
    __shared__ short Bs[128 * 32];
    const int t = threadIdx.x;
    const int w = t >> 6, lane = t & 63;
    const int l15 = lane & 15, quad = lane >> 4;
    const int wr = w >> 1, wc = w & 1;
    const int bm = blockIdx.y * 128, bn = blockIdx.x * 128;
    const int sr = t >> 2, sc = (t & 3) * 8;

    f32x4 acc[4][4];
#pragma unroll
    for (int i = 0; i < 4; ++i)
#pragma unroll
        for (int j = 0; j < 4; ++j) acc[i][j] = (f32x4){0.f, 0.f, 0.f, 0.f};

    for (int k0 = 0; k0 < C; k0 += 32) {
        *(bf16x8*)&As[sr * 32 + sc]        = *(const bf16x8*)&A[(size_t)(bm + sr) * C + k0 + sc];
        *(bf16x8*)&As[(sr + 64) * 32 + sc] = *(const bf16x8*)&A[(size_t)(bm + sr + 64) * C + k0 + sc];
        *(bf16x8*)&Bs[sr * 32 + sc]        = *(const bf16x8*)&Bt[(size_t)(bn + sr) * C + k0 + sc];
        *(bf16x8*)&Bs[(sr + 64) * 32 + sc] = *(const bf16x8*)&Bt[(size_t)(bn + sr + 64) * C + k0 + sc];
        __syncthreads();
        bf16x8 af[4], bfr[4];
#pragma unroll
        for (int i = 0; i < 4; ++i)
            af[i] = *(const bf16x8*)&As[(wr * 64 + i * 16 + l15) * 32 + quad * 8];
#pragma unroll
        for (int j = 0; j < 4; ++j)
            bfr[j] = *(const bf16x8*)&Bs[(wc * 64 + j * 16 + l15) * 32 + quad * 8];
#pragma unroll
        for (int i = 0; i < 4; ++i)
#pragma unroll
            for (int j = 0; j < 4; ++j)
                acc[i][j] = __builtin_amdgcn_mfma_f32_16x16x32_bf16(af[i], bfr[j], acc[i][j], 0, 0, 0);
        __syncthreads();
    }

#pragma unroll
    for (int i = 0; i < 4; ++i)
#pragma unroll
        for (int j = 0; j < 4; ++j) {
            const int n = bn + wc * 64 + j * 16 + l15;
            const float bv = bias[n];
#pragma unroll
            for (int r = 0; r < 4; ++r) {
                const int m = bm + wr * 64 + i * 16 + quad * 4 + r;
                out[(size_t)m * C + n] = acc[i][j][r] + bv;
            }
        }
}

// ---------------------------------------------------------------------------
// attn_stats: per (q-tile 64, bh). MFMA QK^T, online (m,l) per row.
// ---------------------------------------------------------------------------
__global__ __launch_bounds__(256) void attn_stats(
    const short* __restrict__ qs, const short* __restrict__ ks,
    const int* __restrict__ kpm, float* __restrict__ ml)
{
    const int qt = blockIdx.x, bh = blockIdx.y, b = bh >> 4;
    const int q0 = qt * 64;
    const int t = threadIdx.x;
    const int w = t >> 6, lane = t & 63;
    const int l15 = lane & 15, quad = lane >> 4;
    const int qbase = q0 + w * 16;

    const short* qrow = qs + ((size_t)bh * L + qbase + l15) * HD + quad * 8;
    bf16x8 a0 = *(const bf16x8*)(qrow);
    bf16x8 a1 = *(const bf16x8*)(qrow + 32);

    float m[4], lsum[4];
#pragma unroll
    for (int r = 0; r < 4; ++r) { m[r] = -3.0e38f; lsum[r] = 0.f; }

    const int ktiles = qt + 1;
    for (int kt = 0; kt < ktiles; ++kt) {
        const int k0 = kt * 64;
        f32x4 sc[4];
        int kp[4];
#pragma unroll
        for (int nt = 0; nt < 4; ++nt) {
            const short* kr = ks + ((size_t)bh * L + k0 + nt * 16 + l15) * HD + quad * 8;
            bf16x8 b0 = *(const bf16x8*)(kr);
            bf16x8 b1 = *(const bf16x8*)(kr + 32);
            f32x4 c = {0.f, 0.f, 0.f, 0.f};
            c = __builtin_amdgcn_mfma_f32_16x16x32_bf16(a0, b0, c, 0, 0, 0);
            c = __builtin_amdgcn_mfma_f32_16x16x32_bf16(a1, b1, c, 0, 0, 0);
            sc[nt] = c;
            kp[nt] = kpm[(size_t)b * L + k0 + nt * 16 + l15];
        }
#pragma unroll
        for (int r = 0; r < 4; ++r) {
            const int q = qbase + quad * 4 + r;
            float sv[4];
            float tm = -3.0e38f;
#pragma unroll
            for (int nt = 0; nt < 4; ++nt) {
                int k = k0 + nt * 16 + l15;
                bool mk = (k > q) || (kp[nt] != 0);
                float s = mk ? -3.0e38f : sc[nt][r];
                sv[nt] = s;
                tm = fmaxf(tm, s);
            }
            tm = fmaxf(tm, __shfl_xor(tm, 1, 16));
            tm = fmaxf(tm, __shfl_xor(tm, 2, 16));
            tm = fmaxf(tm, __shfl_xor(tm, 4, 16));
            tm = fmaxf(tm, __shfl_xor(tm, 8, 16));
            float nm = fmaxf(m[r], tm);
            float se = 0.f;
#pragma unroll
            for (int nt = 0; nt < 4; ++nt)
                se += (sv[nt] > -1.0e37f) ? __expf(sv[nt] - nm) : 0.f;
            se += __shfl_xor(se, 1, 16);
            se += __shfl_xor(se, 2, 16);
            se += __shfl_xor(se, 4, 16);
            se += __shfl_xor(se, 8, 16);
            lsum[r] = lsum[r] * __expf(m[r] - nm) + se;
            m[r] = nm;
        }
    }

    if (l15 == 0) {
#pragma unroll
        for (int r = 0; r < 4; ++r) {
            int q = qbase + quad * 4 + r;
            ml[((size_t)bh * L + q) * 2] = m[r];
            ml[((size_t)bh * L + q) * 2 + 1] = lsum[r];
        }
    }
}

// ---------------------------------------------------------------------------
// attn_pv: per (q-tile 16, b). 512 thr = 8 waves x 2 heads. O written bf16.
// ---------------------------------------------------------------------------
#define PS 72
__global__ __launch_bounds__(512) void attn_pv(
    const short* __restrict__ qs, const short* __restrict__ ks,
    const short* __restrict__ vt, const float* __restrict__ ml,
    const int* __restrict__ kpm,
    short* __restrict__ ob, float* __restrict__ attn_avg)
{
    const int qt = blockIdx.x, b = blockIdx.y;
    const int q0 = qt * 16;
    const int t = threadIdx.x;
    const int w = t >> 6, lane = t & 63;
    const int l15 = lane & 15, quad = lane >> 4;

    __shared__ short Plds[8][16 * PS];
    __shared__ float avg[8][16][66];
    __shared__ float mls[H][16][2];

    if (t < 256) {
        int h = t >> 4, qq = t & 15;
        mls[h][qq][0] = ml[((size_t)(b * H + h) * L + q0 + qq) * 2];
        mls[h][qq][1] = ml[((size_t)(b * H + h) * L + q0 + qq) * 2 + 1];
    }
    __syncthreads();

    const int h0 = w * 2;
    bf16x8 aq[2][2];
#pragma unroll
    for (int hh = 0; hh < 2; ++hh) {
        const short* qr = qs + ((size_t)(b * H + h0 + hh) * L + q0 + l15) * HD + quad * 8;
        aq[hh][0] = *(const bf16x8*)(qr);
        aq[hh][1] = *(const bf16x8*)(qr + 32);
    }
    float mreg[2][4], il[2][4];
#pragma unroll
    for (int hh = 0; hh < 2; ++hh)
#pragma unroll
        for (int r = 0; r < 4; ++r) {
            mreg[hh][r] = mls[h0 + hh][quad * 4 + r][0];
            float lv = mls[h0 + hh][quad * 4 + r][1];
            il[hh][r] = (lv > 0.f) ? (1.f / lv) : 0.f;
        }

    f32x4 oacc[2][4];
#pragma unroll
    for (int hh = 0; hh < 2; ++hh)
#pragma unroll
        for (int nt = 0; nt < 4; ++nt) oacc[hh][nt] = (f32x4){0.f, 0.f, 0.f, 0.f};

    const int ktiles = (q0 >> 6) + 1;
    for (int kt = 0; kt < ktiles; ++kt) {
        const int k0 = kt * 64;
        int kp[4];
#pragma unroll
        for (int nt = 0; nt < 4; ++nt)
            kp[nt] = kpm[(size_t)b * L + k0 + nt * 16 + l15];

        f32x4 psum[4];
#pragma unroll
        for (int nt = 0; nt < 4; ++nt) psum[nt] = (f32x4){0.f, 0.f, 0.f, 0.f};

#pragma unroll
        for (int hh = 0; hh < 2; ++hh) {
            const int head = h0 + hh;
            const size_t kbase = (size_t)(b * H + head) * L * HD;
            f32x4 sc[4];
#pragma unroll
            for (int nt = 0; nt < 4; ++nt) {
                const short* kr = ks + kbase + (size_t)(k0 + nt * 16 + l15) * HD + quad * 8;
                f32x4 c = {0.f, 0.f, 0.f, 0.f};
                c = __builtin_amdgcn_mfma_f32_16x16x32_bf16(aq[hh][0], *(const bf16x8*)(kr), c, 0, 0, 0);
                c = __builtin_amdgcn_mfma_f32_16x16x32_bf16(aq[hh][1], *(const bf16x8*)(kr + 32), c, 0, 0, 0);
                sc[nt] = c;
            }
#pragma unroll
            for (int nt = 0; nt < 4; ++nt) {
#pragma unroll
                for (int r = 0; r < 4; ++r) {
                    int k = k0 + nt * 16 + l15;
                    int q = q0 + quad * 4 + r;
                    bool mk = (k > q) || (kp[nt] != 0);
                    float p = mk ? 0.f : __expf(sc[nt][r] - mreg[hh][r]) * il[hh][r];
                    psum[nt][r] += p;
                    Plds[w][(quad * 4 + r) * PS + nt * 16 + l15] = f2bf(p);
                }
            }
            __asm__ volatile("s_waitcnt lgkmcnt(0)" ::: "memory");
            bf16x8 pa0 = *(const bf16x8*)(&Plds[w][l15 * PS + quad * 8]);
            bf16x8 pa1 = *(const bf16x8*)(&Plds[w][l15 * PS + 32 + quad * 8]);
            __asm__ volatile("s_waitcnt lgkmcnt(0)" ::: "memory");
            const size_t vbase = (size_t)(b * H + head) * HD * L;
#pragma unroll
            for (int nt = 0; nt < 4; ++nt) {
                const short* vr = vt + vbase + (size_t)(nt * 16 + l15) * L + k0;
                oacc[hh][nt] = __builtin_amdgcn_mfma_f32_16x16x32_bf16(
                    pa0, *(const bf16x8*)(vr + quad * 8), oacc[hh][nt], 0, 0, 0);
                oacc[hh][nt] = __builtin_amdgcn_mfma_f32_16x16x32_bf16(
                    pa1, *(const bf16x8*)(vr + 32 + quad * 8), oacc[hh][nt], 0, 0, 0);
            }
        }

#pragma unroll
        for (int nt = 0; nt < 4; ++nt)
#pragma unroll
            for (int r = 0; r < 4; ++r)
                avg[w][quad * 4 + r][nt * 16 + l15] = psum[nt][r];
        __syncthreads();
        {
            int q = t >> 5, kk = (t & 31) * 2;
            float s0 = 0.f, s1 = 0.f;
#pragma unroll
            for (int ww = 0; ww < 8; ++ww) {
                s0 += avg[ww][q][kk];
                s1 += avg[ww][q][kk + 1];
            }
            float2* dst = (float2*)(attn_avg + ((size_t)b * L + q0 + q) * L + k0 + kk);
            *dst = make_float2(s0 * (1.f / H), s1 * (1.f / H));
        }
        __syncthreads();
    }

    const int kfill = ktiles * 64;
    for (int qq = 0; qq < 16; ++qq) {
        for (int c0 = kfill + t * 4; c0 < L; c0 += 2048) {
            float4* dst = (float4*)(attn_avg + ((size_t)b * L + q0 + qq) * L + c0);
            *dst = make_float4(0.f, 0.f, 0.f, 0.f);
        }
    }

#pragma unroll
    for (int hh = 0; hh < 2; ++hh)
#pragma unroll
        for (int nt = 0; nt < 4; ++nt)
#pragma unroll
            for (int r = 0; r < 4; ++r) {
                int q = q0 + quad * 4 + r;
                int col = (h0 + hh) * HD + nt * 16 + l15;
                ob[((size_t)q * B + b) * C + col] = f2bf(oacc[hh][nt][r]);
            }
}

// ---------------------------------------------------------------------------

extern "C" void kernel_launch(void* const* d_in, const int* in_sizes, int n_in,
                              void* d_out, int out_size, void* d_ws, size_t ws_size,
                              hipStream_t stream) {
    const float* x     = (const float*)d_in[0];
    const float* Wqkv  = (const float*)d_in[1];
    const float* bqkv  = (const float*)d_in[2];
    const float* Wout  = (const float*)d_in[3];
    const float* bout  = (const float*)d_in[4];
    const int* kpm     = (const int*)d_in[6];

    float* out      = (float*)d_out;
    float* attn_avg = out + (size_t)L * B * C;

    const size_t SEG = (size_t)BH * L * HD;      // 4,194,304 elements
    short* xb  = (short*)d_ws;                   // (M, C) bf16
    short* wqt = xb + (size_t)M * C;             // (3C, C) bf16
    short* wot = wqt + (size_t)C3 * C;           // (C, C) bf16
    short* qs  = wot + (size_t)C * C;
    short* ks  = qs + SEG;
    short* vt  = ks + SEG;
    short* ob  = vt + SEG;                       // (M, C) bf16
    float* ml  = (float*)(ob + (size_t)M * C);   // (BH, L, 2) fp32

    cast_bf16<<<dim3((M * C) / (256 * 8)), 256, 0, stream>>>(x, xb);
    transpose_cast<<<dim3(C3 / 32, C / 32), 256, 0, stream>>>(Wqkv, wqt, C, C3);
    transpose_cast<<<dim3(C / 32, C / 32), 256, 0, stream>>>(Wout, wot, C, C);

    qkv_gemm_mfma<<<dim3(C3 / 128, M / 128), 256, 0, stream>>>(xb, wqt, bqkv, qs, ks, vt);
    attn_stats<<<dim3(L / 64, BH), 256, 0, stream>>>(qs, ks, kpm, ml);
    attn_pv<<<dim3(L / 16, B), 512, 0, stream>>>(qs, ks, vt, ml, kpm, ob, attn_avg);
    out_gemm_mfma<<<dim3(C / 128, M / 128), 256, 0, stream>>>(ob, wot, bout, out);
}

// Round 5
// 441.147 us; speedup vs baseline: 12.9196x; 1.2367x over previous
//
#include <hip/hip_runtime.h>
#include <cstddef>

#define L 2048
#define B 2
#define C 1024
#define H 16
#define HD 64
#define BH (B * H)
#define C3 (3 * C)
#define M (L * B)

typedef __attribute__((ext_vector_type(8))) short bf16x8;
typedef __attribute__((ext_vector_type(4))) float f32x4;

__device__ __forceinline__ short f2bf(float f) {
    unsigned u = __builtin_bit_cast(unsigned, f);
    unsigned r = (u + 0x7FFFu + ((u >> 16) & 1u)) >> 16;
    return (short)r;
}

// ---------------------------------------------------------------------------
// Prep kernels
// ---------------------------------------------------------------------------
__global__ __launch_bounds__(256) void cast_bf16(
    const float* __restrict__ src, short* __restrict__ dst)
{
    const size_t i = ((size_t)blockIdx.x * 256 + threadIdx.x) * 8;
    float4 a = *(const float4*)(src + i);
    float4 b = *(const float4*)(src + i + 4);
    bf16x8 o;
    o[0] = f2bf(a.x); o[1] = f2bf(a.y); o[2] = f2bf(a.z); o[3] = f2bf(a.w);
    o[4] = f2bf(b.x); o[5] = f2bf(b.y); o[6] = f2bf(b.z); o[7] = f2bf(b.w);
    *(bf16x8*)(dst + i) = o;
}

__global__ __launch_bounds__(256) void transpose_cast(
    const float* __restrict__ src, short* __restrict__ dst, int R, int Ccols)
{
    __shared__ float tile[32][33];
    const int bx = blockIdx.x * 32;
    const int by = blockIdx.y * 32;
    const int t = threadIdx.x;
    const int tr = t >> 5, tc = t & 31;
#pragma unroll
    for (int p = 0; p < 4; ++p)
        tile[tr + p * 8][tc] = src[(size_t)(by + tr + p * 8) * Ccols + bx + tc];
    __syncthreads();
#pragma unroll
    for (int p = 0; p < 4; ++p)
        dst[(size_t)(bx + tr + p * 8) * R + by + tc] = f2bf(tile[tc][tr + p * 8]);
}

// ---------------------------------------------------------------------------
// bf16 MFMA GEMM, 128x128 tile, BK=32
// ---------------------------------------------------------------------------
__global__ __launch_bounds__(256) void qkv_gemm_mfma(
    const short* __restrict__ A, const short* __restrict__ Bt,
    const float* __restrict__ bias,
    short* __restrict__ qs, short* __restrict__ ks, short* __restrict__ vt)
{
    __shared__ short As[128 * 32];
    __shared__ short Bs[128 * 32];
    const int t = threadIdx.x;
    const int w = t >> 6, lane = t & 63;
    const int l15 = lane & 15, quad = lane >> 4;
    const int wr = w >> 1, wc = w & 1;
    const int bm = blockIdx.y * 128, bn = blockIdx.x * 128;
    const int sr = t >> 2, sc = (t & 3) * 8;

    f32x4 acc[4][4];
#pragma unroll
    for (int i = 0; i < 4; ++i)
#pragma unroll
        for (int j = 0; j < 4; ++j) acc[i][j] = (f32x4){0.f, 0.f, 0.f, 0.f};

    for (int k0 = 0; k0 < C; k0 += 32) {
        *(bf16x8*)&As[sr * 32 + sc]        = *(const bf16x8*)&A[(size_t)(bm + sr) * C + k0 + sc];
        *(bf16x8*)&As[(sr + 64) * 32 + sc] = *(const bf16x8*)&A[(size_t)(bm + sr + 64) * C + k0 + sc];
        *(bf16x8*)&Bs[sr * 32 + sc]        = *(const bf16x8*)&Bt[(size_t)(bn + sr) * C + k0 + sc];
        *(bf16x8*)&Bs[(sr + 64) * 32 + sc] = *(const bf16x8*)&Bt[(size_t)(bn + sr + 64) * C + k0 + sc];
        __syncthreads();
        bf16x8 af[4], bfr[4];
#pragma unroll
        for (int i = 0; i < 4; ++i)
            af[i] = *(const bf16x8*)&As[(wr * 64 + i * 16 + l15) * 32 + quad * 8];
#pragma unroll
        for (int j = 0; j < 4; ++j)
            bfr[j] = *(const bf16x8*)&Bs[(wc * 64 + j * 16 + l15) * 32 + quad * 8];
#pragma unroll
        for (int i = 0; i < 4; ++i)
#pragma unroll
            for (int j = 0; j < 4; ++j)
                acc[i][j] = __builtin_amdgcn_mfma_f32_16x16x32_bf16(af[i], bfr[j], acc[i][j], 0, 0, 0);
        __syncthreads();
    }

#pragma unroll
    for (int i = 0; i < 4; ++i) {
#pragma unroll
        for (int j = 0; j < 4; ++j) {
            const int n = bn + wc * 64 + j * 16 + l15;
            const int part = n >> 10, rem = n & 1023;
            const int h = rem >> 6, d = rem & 63;
            const float bv = bias[n];
#pragma unroll
            for (int r = 0; r < 4; ++r) {
                const int m = bm + wr * 64 + i * 16 + quad * 4 + r;
                const int l = m >> 1, bb = m & 1, bh = bb * H + h;
                float val = acc[i][j][r] + bv;
                if (part == 0)
                    qs[((size_t)bh * L + l) * HD + d] = f2bf(val * 0.125f);
                else if (part == 1)
                    ks[((size_t)bh * L + l) * HD + d] = f2bf(val);
                else
                    vt[((size_t)bh * HD + d) * L + l] = f2bf(val);
            }
        }
    }
}

__global__ __launch_bounds__(256) void out_gemm_mfma(
    const short* __restrict__ A, const short* __restrict__ Bt,
    const float* __restrict__ bias, float* __restrict__ out)
{
    __shared__ short As[128 * 32];
    __shared__ short Bs[128 * 32];
    const int t = threadIdx.x;
    const int w = t >> 6, lane = t & 63;
    const int l15 = lane & 15, quad = lane >> 4;
    const int wr = w >> 1, wc = w & 1;
    const int bm = blockIdx.y * 128, bn = blockIdx.x * 128;
    const int sr = t >> 2, sc = (t & 3) * 8;

    f32x4 acc[4][4];
#pragma unroll
    for (int i = 0; i < 4; ++i)
#pragma unroll
        for (int j = 0; j < 4; ++j) acc[i][j] = (f32x4){0.f, 0.f, 0.f, 0.f};

    for (int k0 = 0; k0 < C; k0 += 32) {
        *(bf16x8*)&As[sr * 32 + sc]        = *(const bf16x8*)&A[(size_t)(bm + sr) * C + k0 + sc];
        *(bf16x8*)&As[(sr + 64) * 32 + sc] = *(const bf16x8*)&A[(size_t)(bm + sr + 64) * C + k0 + sc];
        *(bf16x8*)&Bs[sr * 32 + sc]        = *(const bf16x8*)&Bt[(size_t)(bn + sr) * C + k0 + sc];
        *(bf16x8*)&Bs[(sr + 64) * 32 + sc] = *(const bf16x8*)&Bt[(size_t)(bn + sr + 64) * C + k0 + sc];
        __syncthreads();
        bf16x8 af[4], bfr[4];
#pragma unroll
        for (int i = 0; i < 4; ++i)
            af[i] = *(const bf16x8*)&As[(wr * 64 + i * 16 + l15) * 32 + quad * 8];
#pragma unroll
        for (int j = 0; j < 4; ++j)
            bfr[j] = *(const bf16x8*)&Bs[(wc * 64 + j * 16 + l15) * 32 + quad * 8];
#pragma unroll
        for (int i = 0; i < 4; ++i)
#pragma unroll
            for (int j = 0; j < 4; ++j)
                acc[i][j] = __builtin_amdgcn_mfma_f32_16x16x32_bf16(af[i], bfr[j], acc[i][j], 0, 0, 0);
        __syncthreads();
    }

#pragma unroll
    for (int i = 0; i < 4; ++i)
#pragma unroll
        for (int j = 0; j < 4; ++j) {
            const int n = bn + wc * 64 + j * 16 + l15;
            const float bv = bias[n];
#pragma unroll
            for (int r = 0; r < 4; ++r) {
                const int m = bm + wr * 64 + i * 16 + quad * 4 + r;
                out[(size_t)m * C + n] = acc[i][j][r] + bv;
            }
        }
}

// ---------------------------------------------------------------------------
// attn_fused: flash-style O. Block = (q-pair, bh), 4 waves x 16 q-rows each.
// Online softmax entirely in-wave; NO __syncthreads. Writes m,l for avg pass.
// Pairing qt={x, 31-x} makes all 512 blocks identical work (34 k-tiles).
// ---------------------------------------------------------------------------
#define PS 72
__global__ __launch_bounds__(256) void attn_fused(
    const short* __restrict__ qs, const short* __restrict__ ks,
    const short* __restrict__ vt, const int* __restrict__ kpm,
    short* __restrict__ ob, float* __restrict__ ml)
{
    const int bh = blockIdx.y, b = bh >> 4, h = bh & 15;
    const int t = threadIdx.x;
    const int w = t >> 6, lane = t & 63;
    const int l15 = lane & 15, quad = lane >> 4;
    __shared__ short Plds[4][16 * PS];

    for (int half = 0; half < 2; ++half) {
        const int qt = half ? (31 - (int)blockIdx.x) : (int)blockIdx.x;
        const int qbase = qt * 64 + w * 16;

        const short* qr = qs + ((size_t)bh * L + qbase + l15) * HD + quad * 8;
        bf16x8 a0 = *(const bf16x8*)qr;
        bf16x8 a1 = *(const bf16x8*)(qr + 32);

        float m[4], lsum[4];
#pragma unroll
        for (int r = 0; r < 4; ++r) { m[r] = -3.0e38f; lsum[r] = 0.f; }
        f32x4 oacc[4];
#pragma unroll
        for (int nt = 0; nt < 4; ++nt) oacc[nt] = (f32x4){0.f, 0.f, 0.f, 0.f};

        const int ktiles = qt + 1;
        for (int kt = 0; kt < ktiles; ++kt) {
            const int k0 = kt * 64;
            int kp[4];
#pragma unroll
            for (int nt = 0; nt < 4; ++nt)
                kp[nt] = kpm[(size_t)b * L + k0 + nt * 16 + l15];

            f32x4 sc[4];
#pragma unroll
            for (int nt = 0; nt < 4; ++nt) {
                const short* kr = ks + ((size_t)bh * L + k0 + nt * 16 + l15) * HD + quad * 8;
                f32x4 c = {0.f, 0.f, 0.f, 0.f};
                c = __builtin_amdgcn_mfma_f32_16x16x32_bf16(a0, *(const bf16x8*)kr, c, 0, 0, 0);
                c = __builtin_amdgcn_mfma_f32_16x16x32_bf16(a1, *(const bf16x8*)(kr + 32), c, 0, 0, 0);
                sc[nt] = c;
            }

            float alpha[4];
#pragma unroll
            for (int r = 0; r < 4; ++r) {
                const int q = qbase + quad * 4 + r;
                float sv[4], tm = -3.0e38f;
#pragma unroll
                for (int nt = 0; nt < 4; ++nt) {
                    int k = k0 + nt * 16 + l15;
                    bool mk = (k > q) || (kp[nt] != 0);
                    sv[nt] = mk ? -3.0e38f : sc[nt][r];
                    tm = fmaxf(tm, sv[nt]);
                }
                tm = fmaxf(tm, __shfl_xor(tm, 1, 16));
                tm = fmaxf(tm, __shfl_xor(tm, 2, 16));
                tm = fmaxf(tm, __shfl_xor(tm, 4, 16));
                tm = fmaxf(tm, __shfl_xor(tm, 8, 16));
                const float nm = fmaxf(m[r], tm);
                float se = 0.f;
#pragma unroll
                for (int nt = 0; nt < 4; ++nt) {
                    float pe = (sv[nt] > -1.0e37f) ? __expf(sv[nt] - nm) : 0.f;
                    sc[nt][r] = pe;          // reuse as P (unnormalized)
                    se += pe;
                }
                se += __shfl_xor(se, 1, 16);
                se += __shfl_xor(se, 2, 16);
                se += __shfl_xor(se, 4, 16);
                se += __shfl_xor(se, 8, 16);
                alpha[r] = __expf(m[r] - nm);
                lsum[r] = lsum[r] * alpha[r] + se;
                m[r] = nm;
            }

#pragma unroll
            for (int nt = 0; nt < 4; ++nt)
#pragma unroll
                for (int r = 0; r < 4; ++r)
                    Plds[w][(quad * 4 + r) * PS + nt * 16 + l15] = f2bf(sc[nt][r]);
#pragma unroll
            for (int nt = 0; nt < 4; ++nt)
#pragma unroll
                for (int r = 0; r < 4; ++r)
                    oacc[nt][r] *= alpha[r];

            __asm__ volatile("s_waitcnt lgkmcnt(0)" ::: "memory");
            bf16x8 pa0 = *(const bf16x8*)(&Plds[w][l15 * PS + quad * 8]);
            bf16x8 pa1 = *(const bf16x8*)(&Plds[w][l15 * PS + 32 + quad * 8]);
            __asm__ volatile("s_waitcnt lgkmcnt(0)" ::: "memory");

#pragma unroll
            for (int nt = 0; nt < 4; ++nt) {
                const short* vr = vt + ((size_t)bh * HD + nt * 16 + l15) * L + k0;
                oacc[nt] = __builtin_amdgcn_mfma_f32_16x16x32_bf16(
                    pa0, *(const bf16x8*)(vr + quad * 8), oacc[nt], 0, 0, 0);
                oacc[nt] = __builtin_amdgcn_mfma_f32_16x16x32_bf16(
                    pa1, *(const bf16x8*)(vr + 32 + quad * 8), oacc[nt], 0, 0, 0);
            }
        }

        float il[4];
#pragma unroll
        for (int r = 0; r < 4; ++r) il[r] = (lsum[r] > 0.f) ? (1.f / lsum[r]) : 0.f;

#pragma unroll
        for (int nt = 0; nt < 4; ++nt)
#pragma unroll
            for (int r = 0; r < 4; ++r) {
                int q = qbase + quad * 4 + r;
                int col = h * HD + nt * 16 + l15;
                ob[((size_t)q * B + b) * C + col] = f2bf(oacc[nt][r] * il[r]);
            }
        if (l15 == 0) {
#pragma unroll
            for (int r = 0; r < 4; ++r) {
                int q = qbase + quad * 4 + r;
                ml[((size_t)bh * L + q) * 2] = m[r];
                ml[((size_t)bh * L + q) * 2 + 1] = lsum[r];
            }
        }
    }
}

// ---------------------------------------------------------------------------
// attn_avg_k: block = (kt, qt, b) 64x64 tile. kt>qt -> zero-fill.
// Waves split q-rows (16 each); each wave loops all 16 heads -> avg
// accumulates in-wave, written directly. One __syncthreads (ml staging).
// ---------------------------------------------------------------------------
__global__ __launch_bounds__(256) void attn_avg_k(
    const short* __restrict__ qs, const short* __restrict__ ks,
    const float* __restrict__ ml, const int* __restrict__ kpm,
    float* __restrict__ attn_avg)
{
    const int kt = blockIdx.x, qt = blockIdx.y, b = blockIdx.z;
    const int t = threadIdx.x;
    const int w = t >> 6, lane = t & 63;
    const int l15 = lane & 15, quad = lane >> 4;
    const int qbase = qt * 64 + w * 16;

    if (kt > qt) {
        const float4 z = make_float4(0.f, 0.f, 0.f, 0.f);
#pragma unroll
        for (int e = 0; e < 4; ++e) {
            int idx = lane + e * 64;
            int row = idx >> 4, c4 = (idx & 15) * 4;
            *(float4*)(attn_avg + ((size_t)b * L + qbase + row) * L + kt * 64 + c4) = z;
        }
        return;
    }

    __shared__ float mls[H][64][2];
    for (int i = t; i < H * 64; i += 256) {
        int hh = i >> 6, qq = i & 63;
        float mv = ml[((size_t)(b * H + hh) * L + qt * 64 + qq) * 2];
        float lv = ml[((size_t)(b * H + hh) * L + qt * 64 + qq) * 2 + 1];
        mls[hh][qq][0] = mv;
        mls[hh][qq][1] = (lv > 0.f) ? (1.f / (lv * (float)H)) : 0.f;
    }
    __syncthreads();

    int kp[4];
#pragma unroll
    for (int nt = 0; nt < 4; ++nt)
        kp[nt] = kpm[(size_t)b * L + kt * 64 + nt * 16 + l15];

    f32x4 av[4];
#pragma unroll
    for (int nt = 0; nt < 4; ++nt) av[nt] = (f32x4){0.f, 0.f, 0.f, 0.f};

    for (int hh = 0; hh < H; ++hh) {
        const short* qr = qs + ((size_t)(b * H + hh) * L + qbase + l15) * HD + quad * 8;
        bf16x8 a0 = *(const bf16x8*)qr;
        bf16x8 a1 = *(const bf16x8*)(qr + 32);
        float mv[4], iv[4];
#pragma unroll
        for (int r = 0; r < 4; ++r) {
            mv[r] = mls[hh][w * 16 + quad * 4 + r][0];
            iv[r] = mls[hh][w * 16 + quad * 4 + r][1];
        }
#pragma unroll
        for (int nt = 0; nt < 4; ++nt) {
            const short* kr = ks + ((size_t)(b * H + hh) * L + kt * 64 + nt * 16 + l15) * HD + quad * 8;
            f32x4 c = {0.f, 0.f, 0.f, 0.f};
            c = __builtin_amdgcn_mfma_f32_16x16x32_bf16(a0, *(const bf16x8*)kr, c, 0, 0, 0);
            c = __builtin_amdgcn_mfma_f32_16x16x32_bf16(a1, *(const bf16x8*)(kr + 32), c, 0, 0, 0);
#pragma unroll
            for (int r = 0; r < 4; ++r) {
                int q = qbase + quad * 4 + r;
                int k = kt * 64 + nt * 16 + l15;
                bool mk = (k > q) || (kp[nt] != 0);
                av[nt][r] += mk ? 0.f : __expf(c[r] - mv[r]) * iv[r];
            }
        }
    }

#pragma unroll
    for (int nt = 0; nt < 4; ++nt)
#pragma unroll
        for (int r = 0; r < 4; ++r)
            attn_avg[((size_t)b * L + qbase + quad * 4 + r) * L + kt * 64 + nt * 16 + l15] = av[nt][r];
}

// ---------------------------------------------------------------------------

extern "C" void kernel_launch(void* const* d_in, const int* in_sizes, int n_in,
                              void* d_out, int out_size, void* d_ws, size_t ws_size,
                              hipStream_t stream) {
    const float* x     = (const float*)d_in[0];
    const float* Wqkv  = (const float*)d_in[1];
    const float* bqkv  = (const float*)d_in[2];
    const float* Wout  = (const float*)d_in[3];
    const float* bout  = (const float*)d_in[4];
    const int* kpm     = (const int*)d_in[6];

    float* out      = (float*)d_out;
    float* attn_avg = out + (size_t)L * B * C;

    const size_t SEG = (size_t)BH * L * HD;
    short* xb  = (short*)d_ws;
    short* wqt = xb + (size_t)M * C;
    short* wot = wqt + (size_t)C3 * C;
    short* qs  = wot + (size_t)C * C;
    short* ks  = qs + SEG;
    short* vt  = ks + SEG;
    short* ob  = vt + SEG;
    float* ml  = (float*)(ob + (size_t)M * C);

    cast_bf16<<<dim3((M * C) / (256 * 8)), 256, 0, stream>>>(x, xb);
    transpose_cast<<<dim3(C3 / 32, C / 32), 256, 0, stream>>>(Wqkv, wqt, C, C3);
    transpose_cast<<<dim3(C / 32, C / 32), 256, 0, stream>>>(Wout, wot, C, C);

    qkv_gemm_mfma<<<dim3(C3 / 128, M / 128), 256, 0, stream>>>(xb, wqt, bqkv, qs, ks, vt);
    attn_fused<<<dim3(16, BH), 256, 0, stream>>>(qs, ks, vt, kpm, ob, ml);
    attn_avg_k<<<dim3(L / 64, L / 64, B), 256, 0, stream>>>(qs, ks, ml, kpm, attn_avg);
    out_gemm_mfma<<<dim3(C / 128, M / 128), 256, 0, stream>>>(ob, wot, bout, out);
}

// Round 6
// 404.089 us; speedup vs baseline: 14.1044x; 1.0917x over previous
//
#include <hip/hip_runtime.h>
#include <cstddef>

#define L 2048
#define B 2
#define C 1024
#define H 16
#define HD 64
#define BH (B * H)
#define C3 (3 * C)
#define M (L * B)
#define NTILES 528   // 32*33/2 causal tiles per bh

typedef __attribute__((ext_vector_type(8))) short bf16x8;
typedef __attribute__((ext_vector_type(4))) float f32x4;

__device__ __forceinline__ short f2bf(float f) {
    unsigned u = __builtin_bit_cast(unsigned, f);
    unsigned r = (u + 0x7FFFu + ((u >> 16) & 1u)) >> 16;
    return (short)r;
}
__device__ __forceinline__ float bf2f(short s) {
    return __builtin_bit_cast(float, (unsigned)(unsigned short)s << 16);
}

// ---------------------------------------------------------------------------
// Prep kernels
// ---------------------------------------------------------------------------
__global__ __launch_bounds__(256) void cast_bf16(
    const float* __restrict__ src, short* __restrict__ dst)
{
    const size_t i = ((size_t)blockIdx.x * 256 + threadIdx.x) * 8;
    float4 a = *(const float4*)(src + i);
    float4 b = *(const float4*)(src + i + 4);
    bf16x8 o;
    o[0] = f2bf(a.x); o[1] = f2bf(a.y); o[2] = f2bf(a.z); o[3] = f2bf(a.w);
    o[4] = f2bf(b.x); o[5] = f2bf(b.y); o[6] = f2bf(b.z); o[7] = f2bf(b.w);
    *(bf16x8*)(dst + i) = o;
}

__global__ __launch_bounds__(256) void transpose_cast(
    const float* __restrict__ src, short* __restrict__ dst, int R, int Ccols)
{
    __shared__ float tile[32][33];
    const int bx = blockIdx.x * 32;
    const int by = blockIdx.y * 32;
    const int t = threadIdx.x;
    const int tr = t >> 5, tc = t & 31;
#pragma unroll
    for (int p = 0; p < 4; ++p)
        tile[tr + p * 8][tc] = src[(size_t)(by + tr + p * 8) * Ccols + bx + tc];
    __syncthreads();
#pragma unroll
    for (int p = 0; p < 4; ++p)
        dst[(size_t)(bx + tr + p * 8) * R + by + tc] = f2bf(tile[tc][tr + p * 8]);
}

// ---------------------------------------------------------------------------
// bf16 MFMA GEMM, 128x128 tile, BK=32
// ---------------------------------------------------------------------------
__global__ __launch_bounds__(256) void qkv_gemm_mfma(
    const short* __restrict__ A, const short* __restrict__ Bt,
    const float* __restrict__ bias,
    short* __restrict__ qs, short* __restrict__ ks, short* __restrict__ vt)
{
    __shared__ short As[128 * 32];
    __shared__ short Bs[128 * 32];
    const int t = threadIdx.x;
    const int w = t >> 6, lane = t & 63;
    const int l15 = lane & 15, quad = lane >> 4;
    const int wr = w >> 1, wc = w & 1;
    const int bm = blockIdx.y * 128, bn = blockIdx.x * 128;
    const int sr = t >> 2, sc = (t & 3) * 8;

    f32x4 acc[4][4];
#pragma unroll
    for (int i = 0; i < 4; ++i)
#pragma unroll
        for (int j = 0; j < 4; ++j) acc[i][j] = (f32x4){0.f, 0.f, 0.f, 0.f};

    for (int k0 = 0; k0 < C; k0 += 32) {
        *(bf16x8*)&As[sr * 32 + sc]        = *(const bf16x8*)&A[(size_t)(bm + sr) * C + k0 + sc];
        *(bf16x8*)&As[(sr + 64) * 32 + sc] = *(const bf16x8*)&A[(size_t)(bm + sr + 64) * C + k0 + sc];
        *(bf16x8*)&Bs[sr * 32 + sc]        = *(const bf16x8*)&Bt[(size_t)(bn + sr) * C + k0 + sc];
        *(bf16x8*)&Bs[(sr + 64) * 32 + sc] = *(const bf16x8*)&Bt[(size_t)(bn + sr + 64) * C + k0 + sc];
        __syncthreads();
        bf16x8 af[4], bfr[4];
#pragma unroll
        for (int i = 0; i < 4; ++i)
            af[i] = *(const bf16x8*)&As[(wr * 64 + i * 16 + l15) * 32 + quad * 8];
#pragma unroll
        for (int j = 0; j < 4; ++j)
            bfr[j] = *(const bf16x8*)&Bs[(wc * 64 + j * 16 + l15) * 32 + quad * 8];
#pragma unroll
        for (int i = 0; i < 4; ++i)
#pragma unroll
            for (int j = 0; j < 4; ++j)
                acc[i][j] = __builtin_amdgcn_mfma_f32_16x16x32_bf16(af[i], bfr[j], acc[i][j], 0, 0, 0);
        __syncthreads();
    }

#pragma unroll
    for (int i = 0; i < 4; ++i) {
#pragma unroll
        for (int j = 0; j < 4; ++j) {
            const int n = bn + wc * 64 + j * 16 + l15;
            const int part = n >> 10, rem = n & 1023;
            const int h = rem >> 6, d = rem & 63;
            const float bv = bias[n];
#pragma unroll
            for (int r = 0; r < 4; ++r) {
                const int m = bm + wr * 64 + i * 16 + quad * 4 + r;
                const int l = m >> 1, bb = m & 1, bh = bb * H + h;
                float val = acc[i][j][r] + bv;
                if (part == 0)
                    qs[((size_t)bh * L + l) * HD + d] = f2bf(val * 0.125f);
                else if (part == 1)
                    ks[((size_t)bh * L + l) * HD + d] = f2bf(val);
                else
                    vt[((size_t)bh * HD + d) * L + l] = f2bf(val);
            }
        }
    }
}

__global__ __launch_bounds__(256) void out_gemm_mfma(
    const short* __restrict__ A, const short* __restrict__ Bt,
    const float* __restrict__ bias, float* __restrict__ out)
{
    __shared__ short As[128 * 32];
    __shared__ short Bs[128 * 32];
    const int t = threadIdx.x;
    const int w = t >> 6, lane = t & 63;
    const int l15 = lane & 15, quad = lane >> 4;
    const int wr = w >> 1, wc = w & 1;
    const int bm = blockIdx.y * 128, bn = blockIdx.x * 128;
    const int sr = t >> 2, sc = (t & 3) * 8;

    f32x4 acc[4][4];
#pragma unroll
    for (int i = 0; i < 4; ++i)
#pragma unroll
        for (int j = 0; j < 4; ++j) acc[i][j] = (f32x4){0.f, 0.f, 0.f, 0.f};

    for (int k0 = 0; k0 < C; k0 += 32) {
        *(bf16x8*)&As[sr * 32 + sc]        = *(const bf16x8*)&A[(size_t)(bm + sr) * C + k0 + sc];
        *(bf16x8*)&As[(sr + 64) * 32 + sc] = *(const bf16x8*)&A[(size_t)(bm + sr + 64) * C + k0 + sc];
        *(bf16x8*)&Bs[sr * 32 + sc]        = *(const bf16x8*)&Bt[(size_t)(bn + sr) * C + k0 + sc];
        *(bf16x8*)&Bs[(sr + 64) * 32 + sc] = *(const bf16x8*)&Bt[(size_t)(bn + sr + 64) * C + k0 + sc];
        __syncthreads();
        bf16x8 af[4], bfr[4];
#pragma unroll
        for (int i = 0; i < 4; ++i)
            af[i] = *(const bf16x8*)&As[(wr * 64 + i * 16 + l15) * 32 + quad * 8];
#pragma unroll
        for (int j = 0; j < 4; ++j)
            bfr[j] = *(const bf16x8*)&Bs[(wc * 64 + j * 16 + l15) * 32 + quad * 8];
#pragma unroll
        for (int i = 0; i < 4; ++i)
#pragma unroll
            for (int j = 0; j < 4; ++j)
                acc[i][j] = __builtin_amdgcn_mfma_f32_16x16x32_bf16(af[i], bfr[j], acc[i][j], 0, 0, 0);
        __syncthreads();
    }

#pragma unroll
    for (int i = 0; i < 4; ++i)
#pragma unroll
        for (int j = 0; j < 4; ++j) {
            const int n = bn + wc * 64 + j * 16 + l15;
            const float bv = bias[n];
#pragma unroll
            for (int r = 0; r < 4; ++r) {
                const int m = bm + wr * 64 + i * 16 + quad * 4 + r;
                out[(size_t)m * C + n] = acc[i][j][r] + bv;
            }
        }
}

// ---------------------------------------------------------------------------
// attn_fused: flash-style O. Block = (q-pair, bh), 4 waves x 16 q-rows each.
// NO __syncthreads. Also streams unnormalized P tiles (bf16, causal-packed)
// + per-(q,kt) running max to workspace for the avg reduction pass.
// ---------------------------------------------------------------------------
#define PS 72
__global__ __launch_bounds__(256) void attn_fused(
    const short* __restrict__ qs, const short* __restrict__ ks,
    const short* __restrict__ vt, const int* __restrict__ kpm,
    short* __restrict__ ob, float* __restrict__ ml,
    short* __restrict__ Pbuf, float* __restrict__ mbuf)
{
    const int bh = blockIdx.y, b = bh >> 4, h = bh & 15;
    const int t = threadIdx.x;
    const int w = t >> 6, lane = t & 63;
    const int l15 = lane & 15, quad = lane >> 4;
    __shared__ short Plds[4][16 * PS];

    for (int half = 0; half < 2; ++half) {
        const int qt = half ? (31 - (int)blockIdx.x) : (int)blockIdx.x;
        const int qbase = qt * 64 + w * 16;
        const size_t trow = (size_t)bh * NTILES + (size_t)qt * (qt + 1) / 2;

        const short* qr = qs + ((size_t)bh * L + qbase + l15) * HD + quad * 8;
        bf16x8 a0 = *(const bf16x8*)qr;
        bf16x8 a1 = *(const bf16x8*)(qr + 32);

        float m[4], lsum[4];
#pragma unroll
        for (int r = 0; r < 4; ++r) { m[r] = -3.0e38f; lsum[r] = 0.f; }
        f32x4 oacc[4];
#pragma unroll
        for (int nt = 0; nt < 4; ++nt) oacc[nt] = (f32x4){0.f, 0.f, 0.f, 0.f};

        const int ktiles = qt + 1;
        for (int kt = 0; kt < ktiles; ++kt) {
            const int k0 = kt * 64;
            int kp[4];
#pragma unroll
            for (int nt = 0; nt < 4; ++nt)
                kp[nt] = kpm[(size_t)b * L + k0 + nt * 16 + l15];

            f32x4 sc[4];
#pragma unroll
            for (int nt = 0; nt < 4; ++nt) {
                const short* kr = ks + ((size_t)bh * L + k0 + nt * 16 + l15) * HD + quad * 8;
                f32x4 c = {0.f, 0.f, 0.f, 0.f};
                c = __builtin_amdgcn_mfma_f32_16x16x32_bf16(a0, *(const bf16x8*)kr, c, 0, 0, 0);
                c = __builtin_amdgcn_mfma_f32_16x16x32_bf16(a1, *(const bf16x8*)(kr + 32), c, 0, 0, 0);
                sc[nt] = c;
            }

            float alpha[4];
#pragma unroll
            for (int r = 0; r < 4; ++r) {
                const int q = qbase + quad * 4 + r;
                float sv[4], tm = -3.0e38f;
#pragma unroll
                for (int nt = 0; nt < 4; ++nt) {
                    int k = k0 + nt * 16 + l15;
                    bool mk = (k > q) || (kp[nt] != 0);
                    sv[nt] = mk ? -3.0e38f : sc[nt][r];
                    tm = fmaxf(tm, sv[nt]);
                }
                tm = fmaxf(tm, __shfl_xor(tm, 1, 16));
                tm = fmaxf(tm, __shfl_xor(tm, 2, 16));
                tm = fmaxf(tm, __shfl_xor(tm, 4, 16));
                tm = fmaxf(tm, __shfl_xor(tm, 8, 16));
                const float nm = fmaxf(m[r], tm);
                float se = 0.f;
#pragma unroll
                for (int nt = 0; nt < 4; ++nt) {
                    float pe = (sv[nt] > -1.0e37f) ? __expf(sv[nt] - nm) : 0.f;
                    sc[nt][r] = pe;          // reuse as P (unnormalized)
                    se += pe;
                }
                se += __shfl_xor(se, 1, 16);
                se += __shfl_xor(se, 2, 16);
                se += __shfl_xor(se, 4, 16);
                se += __shfl_xor(se, 8, 16);
                alpha[r] = __expf(m[r] - nm);
                lsum[r] = lsum[r] * alpha[r] + se;
                m[r] = nm;
            }

            // store the running max used for this tile (scale key for avg pass)
            if (l15 == 0) {
#pragma unroll
                for (int r = 0; r < 4; ++r) {
                    int q = qbase + quad * 4 + r;
                    mbuf[((size_t)bh * L + q) * 32 + kt] = m[r];
                }
            }

#pragma unroll
            for (int nt = 0; nt < 4; ++nt)
#pragma unroll
                for (int r = 0; r < 4; ++r)
                    Plds[w][(quad * 4 + r) * PS + nt * 16 + l15] = f2bf(sc[nt][r]);
#pragma unroll
            for (int nt = 0; nt < 4; ++nt)
#pragma unroll
                for (int r = 0; r < 4; ++r)
                    oacc[nt][r] *= alpha[r];

            __asm__ volatile("s_waitcnt lgkmcnt(0)" ::: "memory");
            bf16x8 pa0 = *(const bf16x8*)(&Plds[w][l15 * PS + quad * 8]);
            bf16x8 pa1 = *(const bf16x8*)(&Plds[w][l15 * PS + 32 + quad * 8]);
            __asm__ volatile("s_waitcnt lgkmcnt(0)" ::: "memory");

            // stream P tile to workspace (row = w*16+l15, cols quad*8 / 32+quad*8)
            {
                short* pt = Pbuf + (trow + kt) * 4096 + (w * 16 + l15) * 64;
                *(bf16x8*)(pt + quad * 8) = pa0;
                *(bf16x8*)(pt + 32 + quad * 8) = pa1;
            }

#pragma unroll
            for (int nt = 0; nt < 4; ++nt) {
                const short* vr = vt + ((size_t)bh * HD + nt * 16 + l15) * L + k0;
                oacc[nt] = __builtin_amdgcn_mfma_f32_16x16x32_bf16(
                    pa0, *(const bf16x8*)(vr + quad * 8), oacc[nt], 0, 0, 0);
                oacc[nt] = __builtin_amdgcn_mfma_f32_16x16x32_bf16(
                    pa1, *(const bf16x8*)(vr + 32 + quad * 8), oacc[nt], 0, 0, 0);
            }
        }

        float il[4];
#pragma unroll
        for (int r = 0; r < 4; ++r) il[r] = (lsum[r] > 0.f) ? (1.f / lsum[r]) : 0.f;

#pragma unroll
        for (int nt = 0; nt < 4; ++nt)
#pragma unroll
            for (int r = 0; r < 4; ++r) {
                int q = qbase + quad * 4 + r;
                int col = h * HD + nt * 16 + l15;
                ob[((size_t)q * B + b) * C + col] = f2bf(oacc[nt][r] * il[r]);
            }
        if (l15 == 0) {
#pragma unroll
            for (int r = 0; r < 4; ++r) {
                int q = qbase + quad * 4 + r;
                ml[((size_t)bh * L + q) * 2] = m[r];
                ml[((size_t)bh * L + q) * 2 + 1] = lsum[r];
            }
        }
    }
}

// ---------------------------------------------------------------------------
// attn_avg_r: memory-bound reduction. Block = 64x64 (kt,qt,b) tile.
// kt>qt -> zero-fill; else sum_h Pbuf[h]*exp(m_used-m_fin)/(l_fin*H).
// ---------------------------------------------------------------------------
__global__ __launch_bounds__(256) void attn_avg_r(
    const short* __restrict__ Pbuf, const float* __restrict__ mbuf,
    const float* __restrict__ ml, float* __restrict__ attn_avg)
{
    const int x = blockIdx.x;
    const int kt = x & 31, qt = x >> 5;
    const int b = blockIdx.y;
    const int t = threadIdx.x;
    const int row = t >> 2, cg = (t & 3) * 16;

    float* dst = attn_avg + ((size_t)b * L + qt * 64 + row) * L + kt * 64 + cg;

    if (kt > qt) {
        const float4 z = make_float4(0.f, 0.f, 0.f, 0.f);
#pragma unroll
        for (int e = 0; e < 4; ++e) ((float4*)dst)[e] = z;
        return;
    }

    __shared__ float sc16[16][64];
    for (int i = t; i < 1024; i += 256) {
        int h = i >> 6, rr = i & 63;
        size_t qi = (size_t)(b * 16 + h) * L + qt * 64 + rr;
        float mf = ml[qi * 2], lf = ml[qi * 2 + 1];
        float mu = mbuf[qi * 32 + kt];
        sc16[h][rr] = (lf > 0.f) ? __expf(mu - mf) / (lf * (float)H) : 0.f;
    }
    __syncthreads();

    float acc[16];
#pragma unroll
    for (int e = 0; e < 16; ++e) acc[e] = 0.f;

    const size_t tidx = (size_t)qt * (qt + 1) / 2 + kt;
    for (int h = 0; h < 16; ++h) {
        const short* pb = Pbuf + ((size_t)(b * 16 + h) * NTILES + tidx) * 4096 + row * 64 + cg;
        bf16x8 p0 = *(const bf16x8*)pb;
        bf16x8 p1 = *(const bf16x8*)(pb + 8);
        const float s = sc16[h][row];
#pragma unroll
        for (int e = 0; e < 8; ++e) acc[e] += bf2f(p0[e]) * s;
#pragma unroll
        for (int e = 0; e < 8; ++e) acc[8 + e] += bf2f(p1[e]) * s;
    }
#pragma unroll
    for (int e = 0; e < 4; ++e)
        ((float4*)dst)[e] = make_float4(acc[4 * e], acc[4 * e + 1],
                                        acc[4 * e + 2], acc[4 * e + 3]);
}

// ---------------------------------------------------------------------------

extern "C" void kernel_launch(void* const* d_in, const int* in_sizes, int n_in,
                              void* d_out, int out_size, void* d_ws, size_t ws_size,
                              hipStream_t stream) {
    const float* x     = (const float*)d_in[0];
    const float* Wqkv  = (const float*)d_in[1];
    const float* bqkv  = (const float*)d_in[2];
    const float* Wout  = (const float*)d_in[3];
    const float* bout  = (const float*)d_in[4];
    const int* kpm     = (const int*)d_in[6];

    float* out      = (float*)d_out;
    float* attn_avg = out + (size_t)L * B * C;

    const size_t SEG = (size_t)BH * L * HD;
    short* xb   = (short*)d_ws;                       // 4.19M shorts
    short* wqt  = xb + (size_t)M * C;                 // 3.15M
    short* wot  = wqt + (size_t)C3 * C;               // 1.05M
    short* qs   = wot + (size_t)C * C;                // 4.19M
    short* ks   = qs + SEG;                           // 4.19M
    short* vt   = ks + SEG;                           // 4.19M
    short* ob   = vt + SEG;                           // 4.19M
    float* ml   = (float*)(ob + (size_t)M * C);       // 131K floats
    float* mbuf = ml + (size_t)BH * L * 2;            // 2.10M floats
    short* Pbuf = (short*)(mbuf + (size_t)BH * L * 32); // 69.2M shorts (138 MB)

    cast_bf16<<<dim3((M * C) / (256 * 8)), 256, 0, stream>>>(x, xb);
    transpose_cast<<<dim3(C3 / 32, C / 32), 256, 0, stream>>>(Wqkv, wqt, C, C3);
    transpose_cast<<<dim3(C / 32, C / 32), 256, 0, stream>>>(Wout, wot, C, C);

    qkv_gemm_mfma<<<dim3(C3 / 128, M / 128), 256, 0, stream>>>(xb, wqt, bqkv, qs, ks, vt);
    attn_fused<<<dim3(16, BH), 256, 0, stream>>>(qs, ks, vt, kpm, ob, ml, Pbuf, mbuf);
    attn_avg_r<<<dim3(1024, B), 256, 0, stream>>>(Pbuf, mbuf, ml, attn_avg);
    out_gemm_mfma<<<dim3(C / 128, M / 128), 256, 0, stream>>>(ob, wot, bout, out);
}